// Round 1
// baseline (6648.647 us; speedup 1.0000x reference)
//
#include <hip/hip_runtime.h>
#include <hip/hip_bf16.h>
#include <math.h>

// Problem constants (B=8, S=2048, D=512, I=1024, E=8, K=2, SH=2048)
#define T_TOK 16384
#define DDIM  512
#define IDIM  1024
#define NEXP  8
#define SHDIM 2048

// ---------------- workspace layout (bytes) ----------------
// topi    : int  [2T]      @ 0        (131072 B)
// wts     : f32  [2T]      @ 131072   (131072 B)
// perm    : int  [2T+256]  @ 262144   (132096 B)
// pw      : f32  [2T+256]  @ 394240   (132096 B)
// counts  : int  [8]       @ 526336
// cursors : int  [8]       @ 526592
// off_pad : int  [9]       @ 526848
// psum    : f32  [8]       @ 527104
// total < 1 MB

__global__ void k_zero(int* counts, int* cursors, float* psum) {
    int i = threadIdx.x;
    if (i < NEXP) { counts[i] = 0; cursors[i] = 0; psum[i] = 0.f; }
}

// One wave per token: scores = sigmoid(x @ gate_w^T), top-2, renorm weights.
__global__ __launch_bounds__(256) void k_gate(
    const float* __restrict__ x, const float* __restrict__ gw,
    int* __restrict__ topi, float* __restrict__ wts,
    int* __restrict__ counts, float* __restrict__ psum)
{
    int wid = threadIdx.x >> 6, lane = threadIdx.x & 63;
    int t = blockIdx.x * 4 + wid;
    float acc[NEXP];
#pragma unroll
    for (int e = 0; e < NEXP; e++) acc[e] = 0.f;
    const float* xr = x + (size_t)t * DDIM;
#pragma unroll
    for (int j = 0; j < DDIM / 64; j++) {
        float xv = xr[lane + 64 * j];
#pragma unroll
        for (int e = 0; e < NEXP; e++) acc[e] += xv * gw[e * DDIM + lane + 64 * j];
    }
#pragma unroll
    for (int e = 0; e < NEXP; e++) {
#pragma unroll
        for (int off = 32; off; off >>= 1) acc[e] += __shfl_xor(acc[e], off, 64);
    }
    if (lane == 0) {
        float s[NEXP];
#pragma unroll
        for (int e = 0; e < NEXP; e++) s[e] = 1.f / (1.f + expf(-acc[e]));
        int i1 = 0; float v1 = s[0];
#pragma unroll
        for (int e = 1; e < NEXP; e++) if (s[e] > v1) { v1 = s[e]; i1 = e; }
        int i2 = -1; float v2 = -1.f;
#pragma unroll
        for (int e = 0; e < NEXP; e++) if (e != i1 && s[e] > v2) { v2 = s[e]; i2 = e; }
        float inv = 1.f / (v1 + v2);
        float wa = v1 * inv, wb = v2 * inv;  // ROUTE_SCALE = 1.0
        topi[2 * t] = i1; topi[2 * t + 1] = i2;
        wts[2 * t] = wa;  wts[2 * t + 1] = wb;
        atomicAdd(&counts[i1], 1); atomicAdd(&counts[i2], 1);
        atomicAdd(&psum[i1], wa);  atomicAdd(&psum[i2], wb);
    }
}

// Padded (to 32) exclusive prefix over counts + aux loss.
__global__ void k_scan(const int* __restrict__ counts, int* __restrict__ off_pad,
                       const float* __restrict__ psum, float* __restrict__ out_loss)
{
    if (threadIdx.x == 0 && blockIdx.x == 0) {
        int off = 0; float L = 0.f;
        for (int e = 0; e < NEXP; e++) {
            off_pad[e] = off;
            off += (counts[e] + 31) & ~31;
            float f = (float)NEXP * (float)counts[e] / (float)(2 * T_TOK);
            L += f * (psum[e] / (float)T_TOK);
        }
        off_pad[NEXP] = off;
        out_loss[0] = L;
    }
}

__global__ void k_fillperm(int* __restrict__ perm) {
    int i = blockIdx.x * blockDim.x + threadIdx.x;
    if (i < 2 * T_TOK + 256) perm[i] = -1;
}

__global__ void k_scatter(const int* __restrict__ topi, const float* __restrict__ wts,
                          const int* __restrict__ off_pad, int* __restrict__ cursors,
                          int* __restrict__ perm, float* __restrict__ pw)
{
    int t = blockIdx.x * blockDim.x + threadIdx.x;
    if (t >= T_TOK) return;
#pragma unroll
    for (int k = 0; k < 2; k++) {
        int e = topi[2 * t + k];
        int pos = atomicAdd(&cursors[e], 1);
        int slot = off_pad[e] + pos;
        perm[slot] = t;
        pw[slot] = wts[2 * t + k];
    }
}

// Fused SwiGLU FFN over a 32-token tile, full D output per block.
// GATHER=false: shared expert, writes out = h@w2 + b2 (overwrites).
// GATHER=true : routed expert segment, atomicAdd(pw * (h@w2)) into out.
template <int ID, bool BIAS, bool GATHER>
__global__ __launch_bounds__(256) void k_ffn(
    const float* __restrict__ x,
    const float* __restrict__ w1, const float* __restrict__ b1,
    const float* __restrict__ w3, const float* __restrict__ b3,
    const float* __restrict__ w2, const float* __restrict__ b2,
    const int* __restrict__ off_pad, const int* __restrict__ perm,
    const float* __restrict__ pw, float* __restrict__ out)
{
    __shared__ float xs[32][DDIM];   // 64 KB
    __shared__ float hg[32][64];     // 8 KB
    __shared__ int   toks[32];
    __shared__ float rs[32];

    const int tid = threadIdx.x;
    const int s0  = blockIdx.x * 32;
    const int c   = tid & 63;   // inter/out column lane
    const int r0  = tid >> 6;   // token row group (0..3)

    const float* W1 = w1;
    const float* W3 = w3;
    const float* W2 = w2;
    if (GATHER) {
        if (s0 >= off_pad[NEXP]) return;
        int e = 0;
        while (off_pad[e + 1] <= s0) e++;
        W1 = w1 + (size_t)e * DDIM * ID;
        W3 = w3 + (size_t)e * DDIM * ID;
        W2 = w2 + (size_t)e * ID * DDIM;
    }

    if (tid < 32) {
        int tk;
        if (GATHER) {
            tk = perm[s0 + tid];
            rs[tid] = (tk >= 0) ? pw[s0 + tid] : 0.f;
        } else {
            tk = s0 + tid;
            rs[tid] = 1.f;
        }
        toks[tid] = tk;
    }
    __syncthreads();

    for (int idx = tid; idx < 32 * DDIM; idx += 256) {
        int tt = idx >> 9, d = idx & (DDIM - 1);
        int tk = toks[tt];
        xs[tt][d] = (tk >= 0) ? x[(size_t)tk * DDIM + d] : 0.f;
    }
    __syncthreads();

    float acc2[8][8];
#pragma unroll
    for (int k = 0; k < 8; k++)
#pragma unroll
        for (int q = 0; q < 8; q++) acc2[k][q] = 0.f;

    for (int ic = 0; ic < ID; ic += 64) {
        // ---- phase B: h[tt][c] = silu(x@w1 [+b1]) * (x@w3 [+b3]) for this 64-wide chunk
        float a1[8], a3[8];
        float bb1 = BIAS ? b1[ic + c] : 0.f;
        float bb3 = BIAS ? b3[ic + c] : 0.f;
#pragma unroll
        for (int k = 0; k < 8; k++) { a1[k] = bb1; a3[k] = bb3; }

        const float* p1 = W1 + ic + c;
        const float* p3 = W3 + ic + c;
        for (int d = 0; d < DDIM; d += 4) {
            float w1v[4], w3v[4];
#pragma unroll
            for (int u = 0; u < 4; u++) {
                w1v[u] = p1[(size_t)(d + u) * ID];
                w3v[u] = p3[(size_t)(d + u) * ID];
            }
#pragma unroll
            for (int k = 0; k < 8; k++) {
                float4 xv = *(const float4*)&xs[r0 + 4 * k][d];
                a1[k] += xv.x * w1v[0] + xv.y * w1v[1] + xv.z * w1v[2] + xv.w * w1v[3];
                a3[k] += xv.x * w3v[0] + xv.y * w3v[1] + xv.z * w3v[2] + xv.w * w3v[3];
            }
        }
        __syncthreads();  // previous chunk's hg consumers done
#pragma unroll
        for (int k = 0; k < 8; k++) {
            float v = a1[k];
            float hv = (v / (1.f + expf(-v))) * a3[k];
            hg[r0 + 4 * k][c] = hv;
        }
        __syncthreads();

        // ---- phase C: acc2 += h_chunk @ w2[ic:ic+64, :]
        const float* p2 = W2 + (size_t)ic * DDIM + c;
#pragma unroll 2
        for (int i2 = 0; i2 < 64; i2++) {
            float hvv[8];
#pragma unroll
            for (int k = 0; k < 8; k++) hvv[k] = hg[r0 + 4 * k][i2];
#pragma unroll
            for (int q = 0; q < 8; q++) {
                float wv = p2[(size_t)i2 * DDIM + 64 * q];
#pragma unroll
                for (int k = 0; k < 8; k++) acc2[k][q] += hvv[k] * wv;
            }
        }
    }

    // ---- writeback
#pragma unroll
    for (int k = 0; k < 8; k++) {
        int tt = r0 + 4 * k;
        int tk = toks[tt];
        if (GATHER) {
            if (tk < 0) continue;
            float sc = rs[tt];
            float* orow = out + (size_t)tk * DDIM + c;
#pragma unroll
            for (int q = 0; q < 8; q++) atomicAdd(&orow[64 * q], sc * acc2[k][q]);
        } else {
            float* orow = out + (size_t)tk * DDIM + c;
#pragma unroll
            for (int q = 0; q < 8; q++) orow[64 * q] = acc2[k][q] + (BIAS ? b2[c + 64 * q] : 0.f);
        }
    }
}

extern "C" void kernel_launch(void* const* d_in, const int* in_sizes, int n_in,
                              void* d_out, int out_size, void* d_ws, size_t ws_size,
                              hipStream_t stream)
{
    const float* x   = (const float*)d_in[0];
    const float* gw  = (const float*)d_in[1];
    const float* w1  = (const float*)d_in[2];
    const float* w2  = (const float*)d_in[3];
    const float* w3  = (const float*)d_in[4];
    const float* sw1 = (const float*)d_in[5];
    const float* sb1 = (const float*)d_in[6];
    const float* sw2 = (const float*)d_in[7];
    const float* sb2 = (const float*)d_in[8];
    const float* sw3 = (const float*)d_in[9];
    const float* sb3 = (const float*)d_in[10];
    float* out = (float*)d_out;

    char* ws = (char*)d_ws;
    int*   topi    = (int*)(ws + 0);
    float* wts     = (float*)(ws + 131072);
    int*   perm    = (int*)(ws + 262144);
    float* pw      = (float*)(ws + 394240);
    int*   counts  = (int*)(ws + 526336);
    int*   cursors = (int*)(ws + 526592);
    int*   off_pad = (int*)(ws + 526848);
    float* psum    = (float*)(ws + 527104);

    k_zero<<<1, 64, 0, stream>>>(counts, cursors, psum);
    k_gate<<<T_TOK / 4, 256, 0, stream>>>(x, gw, topi, wts, counts, psum);
    k_scan<<<1, 64, 0, stream>>>(counts, off_pad, psum, out + (size_t)T_TOK * DDIM);
    k_fillperm<<<(2 * T_TOK + 256 + 255) / 256, 256, 0, stream>>>(perm);
    k_scatter<<<(T_TOK + 255) / 256, 256, 0, stream>>>(topi, wts, off_pad, cursors, perm, pw);

    // Shared expert first: overwrites out (poison-safe), then routed atomicAdds on top.
    k_ffn<SHDIM, true, false><<<T_TOK / 32, 256, 0, stream>>>(
        x, sw1, sb1, sw3, sb3, sw2, sb2, nullptr, nullptr, nullptr, out);
    k_ffn<IDIM, false, true><<<(2 * T_TOK + NEXP * 31) / 32 + 1, 256, 0, stream>>>(
        x, w1, nullptr, w3, nullptr, w2, nullptr, off_pad, perm, pw, out);
}

// Round 2
// 957.371 us; speedup vs baseline: 6.9447x; 6.9447x over previous
//
#include <hip/hip_runtime.h>
#include <math.h>
#include <stdint.h>

// B=8,S=2048,D=512,I=1024,E=8,K=2,SH=2048 ; T=16384 tokens
#define T_TOK 16384
#define DDIM  512
#define IDIM  1024
#define NEXP  8
#define SHDIM 2048
#define MT_R  264                  // routed M-tiles (2T + 8*127 padded to 128)
#define MPAD  (MT_R * 128)         // 33792 padded routed rows

typedef unsigned short u16;
typedef short bf16x8 __attribute__((ext_vector_type(8)));
typedef float f32x4 __attribute__((ext_vector_type(4)));

__device__ __forceinline__ u16 f2bf(float f) {
    unsigned u = __float_as_uint(f);
    u += 0x7FFF + ((u >> 16) & 1);   // round-to-nearest-even
    return (u16)(u >> 16);
}

__device__ __forceinline__ void gload_lds16(const void* g, void* l) {
    __builtin_amdgcn_global_load_lds(
        (const __attribute__((address_space(1))) void*)g,
        (__attribute__((address_space(3))) void*)l, 16, 0, 0);
}

// ---------------- routing (proven in round 1) ----------------
__global__ void k_zero(int* counts, int* cursors, float* psum) {
    int i = threadIdx.x;
    if (i < NEXP) { counts[i] = 0; cursors[i] = 0; psum[i] = 0.f; }
}

__global__ __launch_bounds__(256) void k_gate(
    const float* __restrict__ x, const float* __restrict__ gw,
    int* __restrict__ topi, float* __restrict__ wts,
    int* __restrict__ counts, float* __restrict__ psum)
{
    int wid = threadIdx.x >> 6, lane = threadIdx.x & 63;
    int t = blockIdx.x * 4 + wid;
    float acc[NEXP];
#pragma unroll
    for (int e = 0; e < NEXP; e++) acc[e] = 0.f;
    const float* xr = x + (size_t)t * DDIM;
#pragma unroll
    for (int j = 0; j < DDIM / 64; j++) {
        float xv = xr[lane + 64 * j];
#pragma unroll
        for (int e = 0; e < NEXP; e++) acc[e] += xv * gw[e * DDIM + lane + 64 * j];
    }
#pragma unroll
    for (int e = 0; e < NEXP; e++) {
#pragma unroll
        for (int off = 32; off; off >>= 1) acc[e] += __shfl_xor(acc[e], off, 64);
    }
    if (lane == 0) {
        float s[NEXP];
#pragma unroll
        for (int e = 0; e < NEXP; e++) s[e] = 1.f / (1.f + expf(-acc[e]));
        int i1 = 0; float v1 = s[0];
#pragma unroll
        for (int e = 1; e < NEXP; e++) if (s[e] > v1) { v1 = s[e]; i1 = e; }
        int i2 = -1; float v2 = -1.f;
#pragma unroll
        for (int e = 0; e < NEXP; e++) if (e != i1 && s[e] > v2) { v2 = s[e]; i2 = e; }
        float inv = 1.f / (v1 + v2);
        float wa = v1 * inv, wb = v2 * inv;  // ROUTE_SCALE = 1.0
        topi[2 * t] = i1; topi[2 * t + 1] = i2;
        wts[2 * t] = wa;  wts[2 * t + 1] = wb;
        atomicAdd(&counts[i1], 1); atomicAdd(&counts[i2], 1);
        atomicAdd(&psum[i1], wa);  atomicAdd(&psum[i2], wb);
    }
}

__global__ void k_scan(const int* __restrict__ counts, int* __restrict__ off_pad,
                       const float* __restrict__ psum, float* __restrict__ out_loss)
{
    if (threadIdx.x == 0 && blockIdx.x == 0) {
        int off = 0; float L = 0.f;
        for (int e = 0; e < NEXP; e++) {
            off_pad[e] = off;
            off += (counts[e] + 127) & ~127;       // pad segments to 128 (M-tile)
            float f = (float)NEXP * (float)counts[e] / (float)(2 * T_TOK);
            L += f * (psum[e] / (float)T_TOK);
        }
        off_pad[NEXP] = off;
        out_loss[0] = L;
    }
}

__global__ void k_fillperm(int* __restrict__ perm) {
    int i = blockIdx.x * blockDim.x + threadIdx.x;
    if (i < MPAD) perm[i] = -1;
}

__global__ void k_scatter(const int* __restrict__ topi, const float* __restrict__ wts,
                          const int* __restrict__ off_pad, int* __restrict__ cursors,
                          int* __restrict__ perm, float* __restrict__ pw)
{
    int t = blockIdx.x * blockDim.x + threadIdx.x;
    if (t >= T_TOK) return;
#pragma unroll
    for (int k = 0; k < 2; k++) {
        int e = topi[2 * t + k];
        int pos = atomicAdd(&cursors[e], 1);
        int slot = off_pad[e] + pos;
        perm[slot] = t;
        pw[slot] = wts[2 * t + k];
    }
}

// ---------------- conversions ----------------
// x (fp32) -> xb (bf16), elementwise
__global__ __launch_bounds__(256) void k_cvt_x(const float* __restrict__ x, u16* __restrict__ xb) {
    size_t i = ((size_t)blockIdx.x * 256 + threadIdx.x) * 4;
    float4 v = *(const float4*)&x[i];
    ushort4 o = { f2bf(v.x), f2bf(v.y), f2bf(v.z), f2bf(v.w) };
    *(ushort4*)&xb[i] = o;
}

// xg[slot] = bf16(x[perm[slot]]) or 0
__global__ __launch_bounds__(256) void k_gather(const float* __restrict__ x,
                                                const int* __restrict__ perm,
                                                u16* __restrict__ xg) {
    int row = blockIdx.x * 2 + (threadIdx.x >> 7);
    int c = (threadIdx.x & 127) * 4;
    int tok = perm[row];
    ushort4 o = {0, 0, 0, 0};
    if (tok >= 0) {
        float4 v = *(const float4*)&x[(size_t)tok * DDIM + c];
        o = { f2bf(v.x), f2bf(v.y), f2bf(v.z), f2bf(v.w) };
    }
    *(ushort4*)&xg[(size_t)row * DDIM + c] = o;
}

// dst[z][c][r] = bf16(src[z][r][c]) ; grid (C/64, R/64, nmat)
__global__ __launch_bounds__(256) void k_transpose(const float* __restrict__ src,
                                                   u16* __restrict__ dst, int R, int C)
{
    __shared__ u16 t[64][68];
    const float* s = src + (size_t)blockIdx.z * R * C;
    u16* d = dst + (size_t)blockIdx.z * R * C;
    int r0 = blockIdx.y * 64, c0 = blockIdx.x * 64;
    int tid = threadIdx.x;
    int lr = tid >> 4, lc = (tid & 15) * 4;
#pragma unroll
    for (int u = 0; u < 4; u++) {
        int r = lr + u * 16;
        float4 v = *(const float4*)&s[(size_t)(r0 + r) * C + c0 + lc];
        t[lc + 0][r] = f2bf(v.x);
        t[lc + 1][r] = f2bf(v.y);
        t[lc + 2][r] = f2bf(v.z);
        t[lc + 3][r] = f2bf(v.w);
    }
    __syncthreads();
    int wr = tid >> 4, wc = (tid & 15) * 4;
#pragma unroll
    for (int u = 0; u < 4; u++) {
        int c = wr + u * 16;
        ushort4 o = { t[c][wc], t[c][wc + 1], t[c][wc + 2], t[c][wc + 3] };
        *(ushort4*)&d[(size_t)(c0 + c) * R + r0 + wc] = o;
    }
}

// ---------------- MFMA GEMMs (m97 structure: 128x128 tile, BK=32) ----------------
// Stage 1: H = bf16( silu(A@B1 [+bias1]) * (A@B3 [+bias3]) )
// A: [M][K] bf16 row-major ; B1t,B3t: [N][K] bf16 (transposed weights)
template<int K, bool ROUTED, bool BIAS>
__global__ __launch_bounds__(256, 2) void k_s1(
    const u16* __restrict__ A, const u16* __restrict__ B1t, const u16* __restrict__ B3t,
    const float* __restrict__ bias1, const float* __restrict__ bias3,
    u16* __restrict__ H, int ldh, const int* __restrict__ off_pad)
{
    __shared__ __align__(16) u16 sA[128 * 32], sB1[128 * 32], sB3[128 * 32];
    const int m0 = blockIdx.y * 128;
    if (ROUTED && m0 >= off_pad[NEXP]) return;
    const int n0 = blockIdx.x * 128;
    const u16* b1 = B1t; const u16* b3 = B3t;
    if (ROUTED) {
        int e = 0;
        while (off_pad[e + 1] <= m0) e++;
        b1 += (size_t)e * IDIM * DDIM;
        b3 += (size_t)e * IDIM * DDIM;
    }
    const int tid = threadIdx.x;
    const int wid = tid >> 6, lane = tid & 63;
    const int srow = wid * 16 + (lane >> 2);
    const int skk  = (lane & 3) * 8;
    const u16* gA  = A  + (size_t)(m0 + srow) * K + skk;
    const u16* gB1 = b1 + (size_t)(n0 + srow) * K + skk;
    const u16* gB3 = b3 + (size_t)(n0 + srow) * K + skk;
    u16* lA  = sA  + wid * 512;
    u16* lB1 = sB1 + wid * 512;
    u16* lB3 = sB3 + wid * 512;
    const int fr = lane & 15;
    const int fk = (lane >> 4) * 8;
    const int wrow = (wid >> 1) * 64, wcol = (wid & 1) * 64;

    f32x4 acc1[4][4], acc3[4][4];
#pragma unroll
    for (int i = 0; i < 4; i++)
#pragma unroll
        for (int j = 0; j < 4; j++) { acc1[i][j] = {0.f, 0.f, 0.f, 0.f}; acc3[i][j] = {0.f, 0.f, 0.f, 0.f}; }

    for (int k0 = 0; k0 < K; k0 += 32) {
#pragma unroll
        for (int p = 0; p < 2; p++) {
            gload_lds16(gA  + (size_t)p * 64 * K + k0, lA  + p * 2048);
            gload_lds16(gB1 + (size_t)p * 64 * K + k0, lB1 + p * 2048);
            gload_lds16(gB3 + (size_t)p * 64 * K + k0, lB3 + p * 2048);
        }
        __syncthreads();
        bf16x8 av[4], b1v[4], b3v[4];
#pragma unroll
        for (int i = 0; i < 4; i++) {
            av[i]  = *(const bf16x8*)(sA  + (wrow + i * 16 + fr) * 32 + fk);
            b1v[i] = *(const bf16x8*)(sB1 + (wcol + i * 16 + fr) * 32 + fk);
            b3v[i] = *(const bf16x8*)(sB3 + (wcol + i * 16 + fr) * 32 + fk);
        }
#pragma unroll
        for (int i = 0; i < 4; i++)
#pragma unroll
            for (int j = 0; j < 4; j++) {
                acc1[i][j] = __builtin_amdgcn_mfma_f32_16x16x32_bf16(av[i], b1v[j], acc1[i][j], 0, 0, 0);
                acc3[i][j] = __builtin_amdgcn_mfma_f32_16x16x32_bf16(av[i], b3v[j], acc3[i][j], 0, 0, 0);
            }
        __syncthreads();
    }

    const int rr = (lane >> 4) * 4;
#pragma unroll
    for (int i = 0; i < 4; i++) {
#pragma unroll
        for (int j = 0; j < 4; j++) {
            int col = n0 + wcol + j * 16 + fr;
            float bb1 = BIAS ? bias1[col] : 0.f;
            float bb3 = BIAS ? bias3[col] : 0.f;
#pragma unroll
            for (int r = 0; r < 4; r++) {
                int row = m0 + wrow + i * 16 + rr + r;
                float v1 = acc1[i][j][r] + bb1;
                float v3 = acc3[i][j][r] + bb3;
                float hv = (v1 / (1.f + __expf(-v1))) * v3;
                H[(size_t)row * ldh + col] = f2bf(hv);
            }
        }
    }
}

// Stage 2: C = A@B2 ; shared: out[row] = C + b2 (store) ; routed: out[perm[row]] += pw[row]*C (atomic)
template<int K, bool ROUTED>
__global__ __launch_bounds__(256, 2) void k_s2(
    const u16* __restrict__ A, const u16* __restrict__ Bt,
    const float* __restrict__ bias2, float* __restrict__ out,
    const int* __restrict__ off_pad, const int* __restrict__ perm,
    const float* __restrict__ pw)
{
    __shared__ __align__(16) u16 sA[128 * 32], sB[128 * 32];
    const int m0 = blockIdx.y * 128;
    if (ROUTED && m0 >= off_pad[NEXP]) return;
    const int n0 = blockIdx.x * 128;
    const u16* bt = Bt;
    if (ROUTED) {
        int e = 0;
        while (off_pad[e + 1] <= m0) e++;
        bt += (size_t)e * DDIM * IDIM;
    }
    const int tid = threadIdx.x;
    const int wid = tid >> 6, lane = tid & 63;
    const int srow = wid * 16 + (lane >> 2);
    const int skk  = (lane & 3) * 8;
    const u16* gA = A  + (size_t)(m0 + srow) * K + skk;
    const u16* gB = bt + (size_t)(n0 + srow) * K + skk;
    u16* lA = sA + wid * 512;
    u16* lB = sB + wid * 512;
    const int fr = lane & 15;
    const int fk = (lane >> 4) * 8;
    const int wrow = (wid >> 1) * 64, wcol = (wid & 1) * 64;

    f32x4 acc[4][4];
#pragma unroll
    for (int i = 0; i < 4; i++)
#pragma unroll
        for (int j = 0; j < 4; j++) acc[i][j] = {0.f, 0.f, 0.f, 0.f};

    for (int k0 = 0; k0 < K; k0 += 32) {
#pragma unroll
        for (int p = 0; p < 2; p++) {
            gload_lds16(gA + (size_t)p * 64 * K + k0, lA + p * 2048);
            gload_lds16(gB + (size_t)p * 64 * K + k0, lB + p * 2048);
        }
        __syncthreads();
        bf16x8 av[4], bv[4];
#pragma unroll
        for (int i = 0; i < 4; i++) {
            av[i] = *(const bf16x8*)(sA + (wrow + i * 16 + fr) * 32 + fk);
            bv[i] = *(const bf16x8*)(sB + (wcol + i * 16 + fr) * 32 + fk);
        }
#pragma unroll
        for (int i = 0; i < 4; i++)
#pragma unroll
            for (int j = 0; j < 4; j++)
                acc[i][j] = __builtin_amdgcn_mfma_f32_16x16x32_bf16(av[i], bv[j], acc[i][j], 0, 0, 0);
        __syncthreads();
    }

    const int rr = (lane >> 4) * 4;
#pragma unroll
    for (int i = 0; i < 4; i++) {
#pragma unroll
        for (int r = 0; r < 4; r++) {
            int row = m0 + wrow + i * 16 + rr + r;
            int tok = ROUTED ? perm[row] : row;
            float sc = ROUTED ? ((tok >= 0) ? pw[row] : 0.f) : 1.f;
#pragma unroll
            for (int j = 0; j < 4; j++) {
                int col = n0 + wcol + j * 16 + fr;
                float v = acc[i][j][r];
                if (ROUTED) {
                    if (tok >= 0) atomicAdd(&out[(size_t)tok * DDIM + col], sc * v);
                } else {
                    out[(size_t)row * DDIM + col] = v + bias2[col];
                }
            }
        }
    }
}

// ---------------- launch ----------------
extern "C" void kernel_launch(void* const* d_in, const int* in_sizes, int n_in,
                              void* d_out, int out_size, void* d_ws, size_t ws_size,
                              hipStream_t stream)
{
    const float* x   = (const float*)d_in[0];
    const float* gw  = (const float*)d_in[1];
    const float* w1  = (const float*)d_in[2];
    const float* w2  = (const float*)d_in[3];
    const float* w3  = (const float*)d_in[4];
    const float* sw1 = (const float*)d_in[5];
    const float* sb1 = (const float*)d_in[6];
    const float* sw2 = (const float*)d_in[7];
    const float* sb2 = (const float*)d_in[8];
    const float* sw3 = (const float*)d_in[9];
    const float* sb3 = (const float*)d_in[10];
    float* out = (float*)d_out;

    // ---- workspace layout (bytes) ----  total ~145.6 MB
    char* ws = (char*)d_ws;
    size_t off = 0;
    int*   topi    = (int*)(ws + off);   off += (size_t)2 * T_TOK * 4;        // 131072
    float* wts     = (float*)(ws + off); off += (size_t)2 * T_TOK * 4;
    int*   perm    = (int*)(ws + off);   off += (size_t)MPAD * 4;
    float* pw      = (float*)(ws + off); off += (size_t)MPAD * 4;
    int*   counts  = (int*)(ws + off);   off += 256;
    int*   cursors = (int*)(ws + off);   off += 256;
    int*   off_pad = (int*)(ws + off);   off += 256;
    float* psum    = (float*)(ws + off); off += 256;
    u16*   xb      = (u16*)(ws + off);   off += (size_t)T_TOK * DDIM * 2;     // 16.8 MB
    u16*   xg      = (u16*)(ws + off);   off += (size_t)MPAD * DDIM * 2;      // 34.6 MB
    u16*   w1T     = (u16*)(ws + off);   off += (size_t)NEXP * IDIM * DDIM * 2;
    u16*   w3T     = (u16*)(ws + off);   off += (size_t)NEXP * IDIM * DDIM * 2;
    u16*   w2T     = (u16*)(ws + off);   off += (size_t)NEXP * DDIM * IDIM * 2;
    u16*   sw1T    = (u16*)(ws + off);   off += (size_t)SHDIM * DDIM * 2;
    u16*   sw3T    = (u16*)(ws + off);   off += (size_t)SHDIM * DDIM * 2;
    u16*   sw2T    = (u16*)(ws + off);   off += (size_t)DDIM * SHDIM * 2;
    u16*   hb      = (u16*)(ws + off);   off += (size_t)MPAD * IDIM * 2;      // 69.2 MB (reused)

    // routing
    k_zero<<<1, 64, 0, stream>>>(counts, cursors, psum);
    k_gate<<<T_TOK / 4, 256, 0, stream>>>(x, gw, topi, wts, counts, psum);
    k_scan<<<1, 64, 0, stream>>>(counts, off_pad, psum, out + (size_t)T_TOK * DDIM);
    k_fillperm<<<(MPAD + 255) / 256, 256, 0, stream>>>(perm);
    k_scatter<<<(T_TOK + 255) / 256, 256, 0, stream>>>(topi, wts, off_pad, cursors, perm, pw);

    // conversions
    k_cvt_x<<<(int)((size_t)T_TOK * DDIM / 4 / 256), 256, 0, stream>>>(x, xb);
    k_gather<<<MPAD / 2, 256, 0, stream>>>(x, perm, xg);
    k_transpose<<<dim3(IDIM / 64, DDIM / 64, NEXP), 256, 0, stream>>>(w1, w1T, DDIM, IDIM);
    k_transpose<<<dim3(IDIM / 64, DDIM / 64, NEXP), 256, 0, stream>>>(w3, w3T, DDIM, IDIM);
    k_transpose<<<dim3(DDIM / 64, IDIM / 64, NEXP), 256, 0, stream>>>(w2, w2T, IDIM, DDIM);
    k_transpose<<<dim3(SHDIM / 64, DDIM / 64, 1), 256, 0, stream>>>(sw1, sw1T, DDIM, SHDIM);
    k_transpose<<<dim3(SHDIM / 64, DDIM / 64, 1), 256, 0, stream>>>(sw3, sw3T, DDIM, SHDIM);
    k_transpose<<<dim3(DDIM / 64, SHDIM / 64, 1), 256, 0, stream>>>(sw2, sw2T, SHDIM, DDIM);

    // shared expert (writes out = z), then routed experts (atomicAdd on top)
    k_s1<DDIM, false, true><<<dim3(SHDIM / 128, T_TOK / 128), 256, 0, stream>>>(
        xb, sw1T, sw3T, sb1, sb3, hb, SHDIM, nullptr);
    k_s2<SHDIM, false><<<dim3(DDIM / 128, T_TOK / 128), 256, 0, stream>>>(
        hb, sw2T, sb2, out, nullptr, nullptr, nullptr);
    k_s1<DDIM, true, false><<<dim3(IDIM / 128, MT_R), 256, 0, stream>>>(
        xg, w1T, w3T, nullptr, nullptr, hb, IDIM, off_pad);
    k_s2<IDIM, true><<<dim3(DDIM / 128, MT_R), 256, 0, stream>>>(
        hb, w2T, nullptr, out, off_pad, perm, pw);
}

// Round 3
// 432.597 us; speedup vs baseline: 15.3692x; 2.2131x over previous
//
#include <hip/hip_runtime.h>
#include <math.h>
#include <stdint.h>

// B=8,S=2048,D=512,I=1024,E=8,K=2,SH=2048 ; T=16384 tokens
#define T_TOK 16384
#define DDIM  512
#define IDIM  1024
#define NEXP  8
#define SHDIM 2048
#define MT_R  264                  // routed M-tiles (2T + 8*127 padded to 128)
#define MPAD  (MT_R * 128)         // 33792 padded routed rows
#define GBLK  256                  // k_gate blocks (64 tokens each)

typedef unsigned short u16;
typedef short bf16x8 __attribute__((ext_vector_type(8)));
typedef float f32x4 __attribute__((ext_vector_type(4)));

__device__ __forceinline__ u16 f2bf(float f) {
    unsigned u = __float_as_uint(f);
    u += 0x7FFF + ((u >> 16) & 1);   // round-to-nearest-even
    return (u16)(u >> 16);
}

__device__ __forceinline__ void gload_lds16(const void* g, void* l) {
    __builtin_amdgcn_global_load_lds(
        (const __attribute__((address_space(1))) void*)g,
        (__attribute__((address_space(3))) void*)l, 16, 0, 0);
}

// ---------------- routing ----------------
__global__ void k_zero(int* cursors) {
    int i = threadIdx.x;
    if (i < NEXP) cursors[i] = 0;
}

// 64 tokens/block, 4 waves (16 tokens/wave). No global atomics: per-block
// partial counts/psum -> pcnt/pps. Fuses x->bf16 conversion (writes xb).
__global__ __launch_bounds__(256) void k_gate(
    const float* __restrict__ x, const float* __restrict__ gw,
    int* __restrict__ topi, float* __restrict__ wts,
    int* __restrict__ pcnt, float* __restrict__ pps, u16* __restrict__ xb)
{
    __shared__ int   cnt[NEXP];
    __shared__ float ps[NEXP];
    const int tid = threadIdx.x;
    if (tid < NEXP) { cnt[tid] = 0; ps[tid] = 0.f; }
    __syncthreads();
    const int wid = tid >> 6, lane = tid & 63;

    // hoist gate weights: gwr[j][e] = gw[e*512 + lane + 64*j]  (64 regs)
    float gwr[DDIM / 64][NEXP];
#pragma unroll
    for (int j = 0; j < DDIM / 64; j++)
#pragma unroll
        for (int e = 0; e < NEXP; e++) gwr[j][e] = gw[e * DDIM + lane + 64 * j];

    const int t0 = blockIdx.x * 64 + wid * 16;
    for (int u = 0; u < 16; u++) {
        int t = t0 + u;
        const float* xr = x + (size_t)t * DDIM;
        float acc[NEXP];
#pragma unroll
        for (int e = 0; e < NEXP; e++) acc[e] = 0.f;
#pragma unroll
        for (int j = 0; j < DDIM / 64; j++) {
            float xv = xr[lane + 64 * j];
            xb[(size_t)t * DDIM + lane + 64 * j] = f2bf(xv);
#pragma unroll
            for (int e = 0; e < NEXP; e++) acc[e] += xv * gwr[j][e];
        }
#pragma unroll
        for (int e = 0; e < NEXP; e++) {
#pragma unroll
            for (int off = 32; off; off >>= 1) acc[e] += __shfl_xor(acc[e], off, 64);
        }
        if (lane == 0) {
            float s[NEXP];
#pragma unroll
            for (int e = 0; e < NEXP; e++) s[e] = 1.f / (1.f + expf(-acc[e]));
            int i1 = 0; float v1 = s[0];
#pragma unroll
            for (int e = 1; e < NEXP; e++) if (s[e] > v1) { v1 = s[e]; i1 = e; }
            int i2 = -1; float v2 = -1.f;
#pragma unroll
            for (int e = 0; e < NEXP; e++) if (e != i1 && s[e] > v2) { v2 = s[e]; i2 = e; }
            float inv = 1.f / (v1 + v2);
            float wa = v1 * inv, wb = v2 * inv;  // ROUTE_SCALE = 1.0
            topi[2 * t] = i1; topi[2 * t + 1] = i2;
            wts[2 * t] = wa;  wts[2 * t + 1] = wb;
            atomicAdd(&cnt[i1], 1); atomicAdd(&cnt[i2], 1);   // LDS atomics
            atomicAdd(&ps[i1], wa); atomicAdd(&ps[i2], wb);
        }
    }
    __syncthreads();
    if (tid < NEXP) {
        pcnt[blockIdx.x * NEXP + tid] = cnt[tid];
        pps[blockIdx.x * NEXP + tid]  = ps[tid];
    }
}

// Reduce per-block partials; padded exclusive prefix; aux loss. One block, 64 thr.
__global__ void k_scan(const int* __restrict__ pcnt, const float* __restrict__ pps,
                       int* __restrict__ off_pad, float* __restrict__ out_loss)
{
    __shared__ int   scnt[8][NEXP];
    __shared__ float sps[8][NEXP];
    int tid = threadIdx.x;
    if (tid < 64) {
        int e = tid & 7, part = tid >> 3;      // 8 parts x 32 blocks
        int c = 0; float p = 0.f;
        for (int b = part * 32; b < part * 32 + 32; b++) {
            c += pcnt[b * NEXP + e];
            p += pps[b * NEXP + e];
        }
        scnt[part][e] = c; sps[part][e] = p;
    }
    __syncthreads();
    if (tid == 0) {
        int off = 0; float L = 0.f;
        for (int e = 0; e < NEXP; e++) {
            int c = 0; float p = 0.f;
            for (int q = 0; q < 8; q++) { c += scnt[q][e]; p += sps[q][e]; }
            off_pad[e] = off;
            off += (c + 127) & ~127;
            float f = (float)NEXP * (float)c / (float)(2 * T_TOK);
            L += f * (p / (float)T_TOK);
        }
        off_pad[NEXP] = off;
        out_loss[0] = L;
    }
}

__global__ void k_fillperm(int* __restrict__ perm) {
    int i = blockIdx.x * blockDim.x + threadIdx.x;
    if (i < MPAD) perm[i] = -1;
}

// 256 tokens/block: LDS histogram -> one global atomicAdd per expert per block.
__global__ __launch_bounds__(256) void k_scatter(
    const int* __restrict__ topi, const float* __restrict__ wts,
    const int* __restrict__ off_pad, int* __restrict__ cursors,
    int* __restrict__ perm, float* __restrict__ pw)
{
    __shared__ int lcnt[NEXP];
    __shared__ int lbase[NEXP];
    int tid = threadIdx.x;
    if (tid < NEXP) lcnt[tid] = 0;
    __syncthreads();
    int t = blockIdx.x * 256 + tid;
    int e0 = topi[2 * t], e1 = topi[2 * t + 1];
    int p0 = atomicAdd(&lcnt[e0], 1);
    int p1 = atomicAdd(&lcnt[e1], 1);
    __syncthreads();
    if (tid < NEXP) lbase[tid] = atomicAdd(&cursors[tid], lcnt[tid]);
    __syncthreads();
    int s0 = off_pad[e0] + lbase[e0] + p0;
    int s1 = off_pad[e1] + lbase[e1] + p1;
    perm[s0] = t; pw[s0] = wts[2 * t];
    perm[s1] = t; pw[s1] = wts[2 * t + 1];
}

// xg[slot] = xb[perm[slot]] (bf16 copy) or 0
__global__ __launch_bounds__(256) void k_gather(const u16* __restrict__ xb,
                                                const int* __restrict__ perm,
                                                u16* __restrict__ xg) {
    int row = blockIdx.x * 2 + (threadIdx.x >> 7);
    int c = (threadIdx.x & 127) * 4;
    int tok = perm[row];
    ushort4 v = {0, 0, 0, 0};
    if (tok >= 0) v = *(const ushort4*)&xb[(size_t)tok * DDIM + c];
    *(ushort4*)&xg[(size_t)row * DDIM + c] = v;
}

// dst[z][c][r] = bf16(src[z][r][c]) ; grid (C/64, R/64, nmat)
__global__ __launch_bounds__(256) void k_transpose(const float* __restrict__ src,
                                                   u16* __restrict__ dst, int R, int C)
{
    __shared__ u16 t[64][68];
    const float* s = src + (size_t)blockIdx.z * R * C;
    u16* d = dst + (size_t)blockIdx.z * R * C;
    int r0 = blockIdx.y * 64, c0 = blockIdx.x * 64;
    int tid = threadIdx.x;
    int lr = tid >> 4, lc = (tid & 15) * 4;
#pragma unroll
    for (int u = 0; u < 4; u++) {
        int r = lr + u * 16;
        float4 v = *(const float4*)&s[(size_t)(r0 + r) * C + c0 + lc];
        t[lc + 0][r] = f2bf(v.x);
        t[lc + 1][r] = f2bf(v.y);
        t[lc + 2][r] = f2bf(v.z);
        t[lc + 3][r] = f2bf(v.w);
    }
    __syncthreads();
    int wr = tid >> 4, wc = (tid & 15) * 4;
#pragma unroll
    for (int u = 0; u < 4; u++) {
        int c = wr + u * 16;
        ushort4 o = { t[c][wc], t[c][wc + 1], t[c][wc + 2], t[c][wc + 3] };
        *(ushort4*)&d[(size_t)(c0 + c) * R + r0 + wc] = o;
    }
}

// ---------------- MFMA GEMMs (m97 structure: 128x128 tile, BK=32) ----------------
template<int K, bool ROUTED, bool BIAS>
__global__ __launch_bounds__(256, 2) void k_s1(
    const u16* __restrict__ A, const u16* __restrict__ B1t, const u16* __restrict__ B3t,
    const float* __restrict__ bias1, const float* __restrict__ bias3,
    u16* __restrict__ H, int ldh, const int* __restrict__ off_pad)
{
    __shared__ __align__(16) u16 sA[128 * 32], sB1[128 * 32], sB3[128 * 32];
    const int m0 = blockIdx.y * 128;
    if (ROUTED && m0 >= off_pad[NEXP]) return;
    const int n0 = blockIdx.x * 128;
    const u16* b1 = B1t; const u16* b3 = B3t;
    if (ROUTED) {
        int e = 0;
        while (off_pad[e + 1] <= m0) e++;
        b1 += (size_t)e * IDIM * DDIM;
        b3 += (size_t)e * IDIM * DDIM;
    }
    const int tid = threadIdx.x;
    const int wid = tid >> 6, lane = tid & 63;
    const int srow = wid * 16 + (lane >> 2);
    const int skk  = (lane & 3) * 8;
    const u16* gA  = A  + (size_t)(m0 + srow) * K + skk;
    const u16* gB1 = b1 + (size_t)(n0 + srow) * K + skk;
    const u16* gB3 = b3 + (size_t)(n0 + srow) * K + skk;
    u16* lA  = sA  + wid * 512;
    u16* lB1 = sB1 + wid * 512;
    u16* lB3 = sB3 + wid * 512;
    const int fr = lane & 15;
    const int fk = (lane >> 4) * 8;
    const int wrow = (wid >> 1) * 64, wcol = (wid & 1) * 64;

    f32x4 acc1[4][4], acc3[4][4];
#pragma unroll
    for (int i = 0; i < 4; i++)
#pragma unroll
        for (int j = 0; j < 4; j++) { acc1[i][j] = {0.f, 0.f, 0.f, 0.f}; acc3[i][j] = {0.f, 0.f, 0.f, 0.f}; }

    for (int k0 = 0; k0 < K; k0 += 32) {
#pragma unroll
        for (int p = 0; p < 2; p++) {
            gload_lds16(gA  + (size_t)p * 64 * K + k0, lA  + p * 2048);
            gload_lds16(gB1 + (size_t)p * 64 * K + k0, lB1 + p * 2048);
            gload_lds16(gB3 + (size_t)p * 64 * K + k0, lB3 + p * 2048);
        }
        __syncthreads();
        bf16x8 av[4], b1v[4], b3v[4];
#pragma unroll
        for (int i = 0; i < 4; i++) {
            av[i]  = *(const bf16x8*)(sA  + (wrow + i * 16 + fr) * 32 + fk);
            b1v[i] = *(const bf16x8*)(sB1 + (wcol + i * 16 + fr) * 32 + fk);
            b3v[i] = *(const bf16x8*)(sB3 + (wcol + i * 16 + fr) * 32 + fk);
        }
#pragma unroll
        for (int i = 0; i < 4; i++)
#pragma unroll
            for (int j = 0; j < 4; j++) {
                acc1[i][j] = __builtin_amdgcn_mfma_f32_16x16x32_bf16(av[i], b1v[j], acc1[i][j], 0, 0, 0);
                acc3[i][j] = __builtin_amdgcn_mfma_f32_16x16x32_bf16(av[i], b3v[j], acc3[i][j], 0, 0, 0);
            }
        __syncthreads();
    }

    const int rr = (lane >> 4) * 4;
#pragma unroll
    for (int i = 0; i < 4; i++) {
#pragma unroll
        for (int j = 0; j < 4; j++) {
            int col = n0 + wcol + j * 16 + fr;
            float bb1 = BIAS ? bias1[col] : 0.f;
            float bb3 = BIAS ? bias3[col] : 0.f;
#pragma unroll
            for (int r = 0; r < 4; r++) {
                int row = m0 + wrow + i * 16 + rr + r;
                float v1 = acc1[i][j][r] + bb1;
                float v3 = acc3[i][j][r] + bb3;
                float hv = (v1 / (1.f + __expf(-v1))) * v3;
                H[(size_t)row * ldh + col] = f2bf(hv);
            }
        }
    }
}

template<int K, bool ROUTED>
__global__ __launch_bounds__(256, 2) void k_s2(
    const u16* __restrict__ A, const u16* __restrict__ Bt,
    const float* __restrict__ bias2, float* __restrict__ out,
    const int* __restrict__ off_pad, const int* __restrict__ perm,
    const float* __restrict__ pw)
{
    __shared__ __align__(16) u16 sA[128 * 32], sB[128 * 32];
    const int m0 = blockIdx.y * 128;
    if (ROUTED && m0 >= off_pad[NEXP]) return;
    const int n0 = blockIdx.x * 128;
    const u16* bt = Bt;
    if (ROUTED) {
        int e = 0;
        while (off_pad[e + 1] <= m0) e++;
        bt += (size_t)e * DDIM * IDIM;
    }
    const int tid = threadIdx.x;
    const int wid = tid >> 6, lane = tid & 63;
    const int srow = wid * 16 + (lane >> 2);
    const int skk  = (lane & 3) * 8;
    const u16* gA = A  + (size_t)(m0 + srow) * K + skk;
    const u16* gB = bt + (size_t)(n0 + srow) * K + skk;
    u16* lA = sA + wid * 512;
    u16* lB = sB + wid * 512;
    const int fr = lane & 15;
    const int fk = (lane >> 4) * 8;
    const int wrow = (wid >> 1) * 64, wcol = (wid & 1) * 64;

    f32x4 acc[4][4];
#pragma unroll
    for (int i = 0; i < 4; i++)
#pragma unroll
        for (int j = 0; j < 4; j++) acc[i][j] = {0.f, 0.f, 0.f, 0.f};

    for (int k0 = 0; k0 < K; k0 += 32) {
#pragma unroll
        for (int p = 0; p < 2; p++) {
            gload_lds16(gA + (size_t)p * 64 * K + k0, lA + p * 2048);
            gload_lds16(gB + (size_t)p * 64 * K + k0, lB + p * 2048);
        }
        __syncthreads();
        bf16x8 av[4], bv[4];
#pragma unroll
        for (int i = 0; i < 4; i++) {
            av[i] = *(const bf16x8*)(sA + (wrow + i * 16 + fr) * 32 + fk);
            bv[i] = *(const bf16x8*)(sB + (wcol + i * 16 + fr) * 32 + fk);
        }
#pragma unroll
        for (int i = 0; i < 4; i++)
#pragma unroll
            for (int j = 0; j < 4; j++)
                acc[i][j] = __builtin_amdgcn_mfma_f32_16x16x32_bf16(av[i], bv[j], acc[i][j], 0, 0, 0);
        __syncthreads();
    }

    const int rr = (lane >> 4) * 4;
#pragma unroll
    for (int i = 0; i < 4; i++) {
#pragma unroll
        for (int r = 0; r < 4; r++) {
            int row = m0 + wrow + i * 16 + rr + r;
            int tok = ROUTED ? perm[row] : row;
            float sc = ROUTED ? ((tok >= 0) ? pw[row] : 0.f) : 1.f;
#pragma unroll
            for (int j = 0; j < 4; j++) {
                int col = n0 + wcol + j * 16 + fr;
                float v = acc[i][j][r];
                if (ROUTED) {
                    if (tok >= 0) atomicAdd(&out[(size_t)tok * DDIM + col], sc * v);
                } else {
                    out[(size_t)row * DDIM + col] = v + bias2[col];
                }
            }
        }
    }
}

// ---------------- launch ----------------
extern "C" void kernel_launch(void* const* d_in, const int* in_sizes, int n_in,
                              void* d_out, int out_size, void* d_ws, size_t ws_size,
                              hipStream_t stream)
{
    const float* x   = (const float*)d_in[0];
    const float* gw  = (const float*)d_in[1];
    const float* w1  = (const float*)d_in[2];
    const float* w2  = (const float*)d_in[3];
    const float* w3  = (const float*)d_in[4];
    const float* sw1 = (const float*)d_in[5];
    const float* sb1 = (const float*)d_in[6];
    const float* sw2 = (const float*)d_in[7];
    const float* sb2 = (const float*)d_in[8];
    const float* sw3 = (const float*)d_in[9];
    const float* sb3 = (const float*)d_in[10];
    float* out = (float*)d_out;

    char* ws = (char*)d_ws;
    size_t off = 0;
    int*   topi    = (int*)(ws + off);   off += (size_t)2 * T_TOK * 4;
    float* wts     = (float*)(ws + off); off += (size_t)2 * T_TOK * 4;
    int*   perm    = (int*)(ws + off);   off += (size_t)MPAD * 4;
    float* pw      = (float*)(ws + off); off += (size_t)MPAD * 4;
    int*   cursors = (int*)(ws + off);   off += 256;
    int*   off_pad = (int*)(ws + off);   off += 256;
    int*   pcnt    = (int*)(ws + off);   off += (size_t)GBLK * NEXP * 4;
    float* pps     = (float*)(ws + off); off += (size_t)GBLK * NEXP * 4;
    u16*   xb      = (u16*)(ws + off);   off += (size_t)T_TOK * DDIM * 2;
    u16*   xg      = (u16*)(ws + off);   off += (size_t)MPAD * DDIM * 2;
    u16*   w1T     = (u16*)(ws + off);   off += (size_t)NEXP * IDIM * DDIM * 2;
    u16*   w3T     = (u16*)(ws + off);   off += (size_t)NEXP * IDIM * DDIM * 2;
    u16*   w2T     = (u16*)(ws + off);   off += (size_t)NEXP * DDIM * IDIM * 2;
    u16*   sw1T    = (u16*)(ws + off);   off += (size_t)SHDIM * DDIM * 2;
    u16*   sw3T    = (u16*)(ws + off);   off += (size_t)SHDIM * DDIM * 2;
    u16*   sw2T    = (u16*)(ws + off);   off += (size_t)DDIM * SHDIM * 2;
    u16*   hb      = (u16*)(ws + off);   off += (size_t)MPAD * IDIM * 2;

    // routing (atomic-free gate; block-aggregated scatter)
    k_zero<<<1, 64, 0, stream>>>(cursors);
    k_gate<<<GBLK, 256, 0, stream>>>(x, gw, topi, wts, pcnt, pps, xb);
    k_scan<<<1, 64, 0, stream>>>(pcnt, pps, off_pad, out + (size_t)T_TOK * DDIM);
    k_fillperm<<<(MPAD + 255) / 256, 256, 0, stream>>>(perm);
    k_scatter<<<T_TOK / 256, 256, 0, stream>>>(topi, wts, off_pad, cursors, perm, pw);

    // conversions
    k_gather<<<MPAD / 2, 256, 0, stream>>>(xb, perm, xg);
    k_transpose<<<dim3(IDIM / 64, DDIM / 64, NEXP), 256, 0, stream>>>(w1, w1T, DDIM, IDIM);
    k_transpose<<<dim3(IDIM / 64, DDIM / 64, NEXP), 256, 0, stream>>>(w3, w3T, DDIM, IDIM);
    k_transpose<<<dim3(DDIM / 64, IDIM / 64, NEXP), 256, 0, stream>>>(w2, w2T, IDIM, DDIM);
    k_transpose<<<dim3(SHDIM / 64, DDIM / 64, 1), 256, 0, stream>>>(sw1, sw1T, DDIM, SHDIM);
    k_transpose<<<dim3(SHDIM / 64, DDIM / 64, 1), 256, 0, stream>>>(sw3, sw3T, DDIM, SHDIM);
    k_transpose<<<dim3(DDIM / 64, SHDIM / 64, 1), 256, 0, stream>>>(sw2, sw2T, SHDIM, DDIM);

    // shared expert (writes out = z), then routed experts (atomicAdd on top)
    k_s1<DDIM, false, true><<<dim3(SHDIM / 128, T_TOK / 128), 256, 0, stream>>>(
        xb, sw1T, sw3T, sb1, sb3, hb, SHDIM, nullptr);
    k_s2<SHDIM, false><<<dim3(DDIM / 128, T_TOK / 128), 256, 0, stream>>>(
        hb, sw2T, sb2, out, nullptr, nullptr, nullptr);
    k_s1<DDIM, true, false><<<dim3(IDIM / 128, MT_R), 256, 0, stream>>>(
        xg, w1T, w3T, nullptr, nullptr, hb, IDIM, off_pad);
    k_s2<IDIM, true><<<dim3(DDIM / 128, MT_R), 256, 0, stream>>>(
        hb, w2T, nullptr, out, off_pad, perm, pw);
}

// Round 4
// 387.166 us; speedup vs baseline: 17.1726x; 1.1173x over previous
//
#include <hip/hip_runtime.h>
#include <math.h>
#include <stdint.h>

// B=8,S=2048,D=512,I=1024,E=8,K=2,SH=2048 ; T=16384 tokens
#define T_TOK 16384
#define DDIM  512
#define IDIM  1024
#define NEXP  8
#define SHDIM 2048
#define MT_R  264                  // routed M-tiles (2T + 8*127 padded to 128)
#define MPAD  (MT_R * 128)         // 33792 padded routed rows
#define GBLK  256                  // k_gate blocks (64 tokens each)

typedef unsigned short u16;
typedef short bf16x8 __attribute__((ext_vector_type(8)));
typedef float f32x4 __attribute__((ext_vector_type(4)));

__device__ __forceinline__ u16 f2bf(float f) {
    unsigned u = __float_as_uint(f);
    u += 0x7FFF + ((u >> 16) & 1);   // round-to-nearest-even
    return (u16)(u >> 16);
}
__device__ __forceinline__ float bf2f(u16 h) {
    return __uint_as_float((unsigned)h << 16);
}

__device__ __forceinline__ void gload_lds16(const void* g, void* l) {
    __builtin_amdgcn_global_load_lds(
        (const __attribute__((address_space(1))) void*)g,
        (__attribute__((address_space(3))) void*)l, 16, 0, 0);
}

// XCD-chunked bijective block swizzle (T1); nwg % 8 == 0 for all our grids.
__device__ __forceinline__ int xcd_swz(int id, int nwg) {
    return (id & 7) * (nwg >> 3) + (id >> 3);
}

// ---------------- routing ----------------
__global__ void k_zero(int* cursors) {
    int i = threadIdx.x;
    if (i < NEXP) cursors[i] = 0;
}

// 64 tokens/block, 4 waves (16 tokens/wave). No global atomics; fuses x->bf16.
__global__ __launch_bounds__(256) void k_gate(
    const float* __restrict__ x, const float* __restrict__ gw,
    int* __restrict__ topi, float* __restrict__ wts,
    int* __restrict__ pcnt, float* __restrict__ pps, u16* __restrict__ xb)
{
    __shared__ int   cnt[NEXP];
    __shared__ float ps[NEXP];
    const int tid = threadIdx.x;
    if (tid < NEXP) { cnt[tid] = 0; ps[tid] = 0.f; }
    __syncthreads();
    const int wid = tid >> 6, lane = tid & 63;

    const float4* gw4 = (const float4*)gw;
    float4 g0[NEXP], g1[NEXP];
#pragma unroll
    for (int e = 0; e < NEXP; e++) {
        g0[e] = gw4[e * 128 + lane];
        g1[e] = gw4[e * 128 + 64 + lane];
    }

    const int t0 = blockIdx.x * 64 + wid * 16;
    for (int u = 0; u < 16; u++) {
        int t = t0 + u;
        const float4* xr4 = (const float4*)(x + (size_t)t * DDIM);
        float4 v0 = xr4[lane];
        float4 v1 = xr4[64 + lane];
        ushort4 o0 = { f2bf(v0.x), f2bf(v0.y), f2bf(v0.z), f2bf(v0.w) };
        ushort4 o1 = { f2bf(v1.x), f2bf(v1.y), f2bf(v1.z), f2bf(v1.w) };
        ushort4* xbo = (ushort4*)(xb + (size_t)t * DDIM);
        xbo[lane] = o0;
        xbo[64 + lane] = o1;
        float acc[NEXP];
#pragma unroll
        for (int e = 0; e < NEXP; e++) {
            acc[e] = v0.x * g0[e].x + v0.y * g0[e].y + v0.z * g0[e].z + v0.w * g0[e].w
                   + v1.x * g1[e].x + v1.y * g1[e].y + v1.z * g1[e].z + v1.w * g1[e].w;
        }
#pragma unroll
        for (int e = 0; e < NEXP; e++) {
#pragma unroll
            for (int off = 32; off; off >>= 1) acc[e] += __shfl_xor(acc[e], off, 64);
        }
        if (lane == 0) {
            float s[NEXP];
#pragma unroll
            for (int e = 0; e < NEXP; e++) s[e] = 1.f / (1.f + expf(-acc[e]));
            int i1 = 0; float v1s = s[0];
#pragma unroll
            for (int e = 1; e < NEXP; e++) if (s[e] > v1s) { v1s = s[e]; i1 = e; }
            int i2 = -1; float v2s = -1.f;
#pragma unroll
            for (int e = 0; e < NEXP; e++) if (e != i1 && s[e] > v2s) { v2s = s[e]; i2 = e; }
            float inv = 1.f / (v1s + v2s);
            float wa = v1s * inv, wb = v2s * inv;  // ROUTE_SCALE = 1.0
            topi[2 * t] = i1; topi[2 * t + 1] = i2;
            wts[2 * t] = wa;  wts[2 * t + 1] = wb;
            atomicAdd(&cnt[i1], 1); atomicAdd(&cnt[i2], 1);   // LDS atomics
            atomicAdd(&ps[i1], wa); atomicAdd(&ps[i2], wb);
        }
    }
    __syncthreads();
    if (tid < NEXP) {
        pcnt[blockIdx.x * NEXP + tid] = cnt[tid];
        pps[blockIdx.x * NEXP + tid]  = ps[tid];
    }
}

// Reduce per-block partials; padded exclusive prefix; aux loss.
__global__ void k_scan(const int* __restrict__ pcnt, const float* __restrict__ pps,
                       int* __restrict__ off_pad, float* __restrict__ out_loss)
{
    __shared__ int   scnt[8][NEXP];
    __shared__ float sps[8][NEXP];
    int tid = threadIdx.x;
    if (tid < 64) {
        int e = tid & 7, part = tid >> 3;      // 8 parts x 32 blocks
        int c = 0; float p = 0.f;
        for (int b = part * 32; b < part * 32 + 32; b++) {
            c += pcnt[b * NEXP + e];
            p += pps[b * NEXP + e];
        }
        scnt[part][e] = c; sps[part][e] = p;
    }
    __syncthreads();
    if (tid == 0) {
        int off = 0; float L = 0.f;
        for (int e = 0; e < NEXP; e++) {
            int c = 0; float p = 0.f;
            for (int q = 0; q < 8; q++) { c += scnt[q][e]; p += sps[q][e]; }
            off_pad[e] = off;
            off += (c + 127) & ~127;
            float f = (float)NEXP * (float)c / (float)(2 * T_TOK);
            L += f * (p / (float)T_TOK);
        }
        off_pad[NEXP] = off;
        out_loss[0] = L;
    }
}

__global__ void k_fillperm(int* __restrict__ perm) {
    int i = blockIdx.x * blockDim.x + threadIdx.x;
    if (i < MPAD) perm[i] = -1;
}

// 256 tokens/block: LDS histogram -> one global atomicAdd per expert per block.
// Also records inverse map inv[2t+k] = slot.
__global__ __launch_bounds__(256) void k_scatter(
    const int* __restrict__ topi, const float* __restrict__ wts,
    const int* __restrict__ off_pad, int* __restrict__ cursors,
    int* __restrict__ perm, float* __restrict__ pw, int* __restrict__ inv)
{
    __shared__ int lcnt[NEXP];
    __shared__ int lbase[NEXP];
    int tid = threadIdx.x;
    if (tid < NEXP) lcnt[tid] = 0;
    __syncthreads();
    int t = blockIdx.x * 256 + tid;
    int e0 = topi[2 * t], e1 = topi[2 * t + 1];
    int p0 = atomicAdd(&lcnt[e0], 1);
    int p1 = atomicAdd(&lcnt[e1], 1);
    __syncthreads();
    if (tid < NEXP) lbase[tid] = atomicAdd(&cursors[tid], lcnt[tid]);
    __syncthreads();
    int s0 = off_pad[e0] + lbase[e0] + p0;
    int s1 = off_pad[e1] + lbase[e1] + p1;
    perm[s0] = t; pw[s0] = wts[2 * t];
    perm[s1] = t; pw[s1] = wts[2 * t + 1];
    inv[2 * t] = s0; inv[2 * t + 1] = s1;
}

// xg[slot] = xb[perm[slot]] (bf16 copy) or 0
__global__ __launch_bounds__(256) void k_gather(const u16* __restrict__ xb,
                                                const int* __restrict__ perm,
                                                u16* __restrict__ xg) {
    int row = blockIdx.x * 2 + (threadIdx.x >> 7);
    int c = (threadIdx.x & 127) * 4;
    int tok = perm[row];
    ushort4 v = {0, 0, 0, 0};
    if (tok >= 0) v = *(const ushort4*)&xb[(size_t)tok * DDIM + c];
    *(ushort4*)&xg[(size_t)row * DDIM + c] = v;
}

// dst[z][c][r] = bf16(src[z][r][c]) ; grid (C/64, R/64, nmat)
__global__ __launch_bounds__(256) void k_transpose(const float* __restrict__ src,
                                                   u16* __restrict__ dst, int R, int C)
{
    __shared__ u16 t[64][68];
    const float* s = src + (size_t)blockIdx.z * R * C;
    u16* d = dst + (size_t)blockIdx.z * R * C;
    int r0 = blockIdx.y * 64, c0 = blockIdx.x * 64;
    int tid = threadIdx.x;
    int lr = tid >> 4, lc = (tid & 15) * 4;
#pragma unroll
    for (int u = 0; u < 4; u++) {
        int r = lr + u * 16;
        float4 v = *(const float4*)&s[(size_t)(r0 + r) * C + c0 + lc];
        t[lc + 0][r] = f2bf(v.x);
        t[lc + 1][r] = f2bf(v.y);
        t[lc + 2][r] = f2bf(v.z);
        t[lc + 3][r] = f2bf(v.w);
    }
    __syncthreads();
    int wr = tid >> 4, wc = (tid & 15) * 4;
#pragma unroll
    for (int u = 0; u < 4; u++) {
        int c = wr + u * 16;
        ushort4 o = { t[c][wc], t[c][wc + 1], t[c][wc + 2], t[c][wc + 3] };
        *(ushort4*)&d[(size_t)(c0 + c) * R + r0 + wc] = o;
    }
}

// ---------------- MFMA GEMMs (128x128 tile, BK=32, double-buffered 2-phase) ----------------
// Stage 1: H = bf16( silu(A@B1 [+bias1]) * (A@B3 [+bias3]) )
template<int K, bool ROUTED, bool BIAS>
__global__ __launch_bounds__(256, 2) void k_s1(
    const u16* __restrict__ A, const u16* __restrict__ B1t, const u16* __restrict__ B3t,
    const float* __restrict__ bias1, const float* __restrict__ bias3,
    u16* __restrict__ H, int ldh, const int* __restrict__ off_pad)
{
    __shared__ __align__(16) u16 sA[2][128 * 32], sB1[2][128 * 32], sB3[2][128 * 32]; // 48 KB
    const int nwg = gridDim.x * gridDim.y;
    const int id  = xcd_swz(blockIdx.y * gridDim.x + blockIdx.x, nwg);
    const int m0 = (id / gridDim.x) * 128;
    const int n0 = (id % gridDim.x) * 128;
    if (ROUTED && m0 >= off_pad[NEXP]) return;
    const u16* b1 = B1t; const u16* b3 = B3t;
    if (ROUTED) {
        int e = 0;
        while (off_pad[e + 1] <= m0) e++;
        b1 += (size_t)e * IDIM * DDIM;
        b3 += (size_t)e * IDIM * DDIM;
    }
    const int tid = threadIdx.x;
    const int wid = tid >> 6, lane = tid & 63;
    const int srow = wid * 16 + (lane >> 2);
    const int skk  = (lane & 3) * 8;
    const u16* gA  = A  + (size_t)(m0 + srow) * K + skk;
    const u16* gB1 = b1 + (size_t)(n0 + srow) * K + skk;
    const u16* gB3 = b3 + (size_t)(n0 + srow) * K + skk;
    const int ldst = wid * 512;          // element offset of this wave's stage region
    const int fr = lane & 15;
    const int fk = (lane >> 4) * 8;
    const int wrow = (wid >> 1) * 64, wcol = (wid & 1) * 64;

    f32x4 acc1[4][4], acc3[4][4];
#pragma unroll
    for (int i = 0; i < 4; i++)
#pragma unroll
        for (int j = 0; j < 4; j++) { acc1[i][j] = {0.f, 0.f, 0.f, 0.f}; acc3[i][j] = {0.f, 0.f, 0.f, 0.f}; }

    // prologue: stage tile 0
#pragma unroll
    for (int p = 0; p < 2; p++) {
        gload_lds16(gA  + (size_t)p * 64 * K, &sA [0][ldst + p * 2048]);
        gload_lds16(gB1 + (size_t)p * 64 * K, &sB1[0][ldst + p * 2048]);
        gload_lds16(gB3 + (size_t)p * 64 * K, &sB3[0][ldst + p * 2048]);
    }
    __syncthreads();

    int cur = 0;
    for (int k0 = 0; k0 < K; k0 += 32) {
        if (k0 + 32 < K) {                 // prefetch next tile into buf^1
#pragma unroll
            for (int p = 0; p < 2; p++) {
                gload_lds16(gA  + (size_t)p * 64 * K + k0 + 32, &sA [cur ^ 1][ldst + p * 2048]);
                gload_lds16(gB1 + (size_t)p * 64 * K + k0 + 32, &sB1[cur ^ 1][ldst + p * 2048]);
                gload_lds16(gB3 + (size_t)p * 64 * K + k0 + 32, &sB3[cur ^ 1][ldst + p * 2048]);
            }
        }
        bf16x8 av[4], b1v[4], b3v[4];
#pragma unroll
        for (int i = 0; i < 4; i++) {
            av[i]  = *(const bf16x8*)(&sA [cur][(wrow + i * 16 + fr) * 32 + fk]);
            b1v[i] = *(const bf16x8*)(&sB1[cur][(wcol + i * 16 + fr) * 32 + fk]);
            b3v[i] = *(const bf16x8*)(&sB3[cur][(wcol + i * 16 + fr) * 32 + fk]);
        }
#pragma unroll
        for (int i = 0; i < 4; i++)
#pragma unroll
            for (int j = 0; j < 4; j++) {
                acc1[i][j] = __builtin_amdgcn_mfma_f32_16x16x32_bf16(av[i], b1v[j], acc1[i][j], 0, 0, 0);
                acc3[i][j] = __builtin_amdgcn_mfma_f32_16x16x32_bf16(av[i], b3v[j], acc3[i][j], 0, 0, 0);
            }
        __syncthreads();                   // drains prefetch (vmcnt) + protects buf reuse
        cur ^= 1;
    }

    const int rr = (lane >> 4) * 4;
#pragma unroll
    for (int i = 0; i < 4; i++) {
#pragma unroll
        for (int j = 0; j < 4; j++) {
            int col = n0 + wcol + j * 16 + fr;
            float bb1 = BIAS ? bias1[col] : 0.f;
            float bb3 = BIAS ? bias3[col] : 0.f;
#pragma unroll
            for (int r = 0; r < 4; r++) {
                int row = m0 + wrow + i * 16 + rr + r;
                float v1 = acc1[i][j][r] + bb1;
                float v3 = acc3[i][j][r] + bb3;
                float hv = (v1 / (1.f + __expf(-v1))) * v3;
                H[(size_t)row * ldh + col] = f2bf(hv);
            }
        }
    }
}

// Stage 2: C = A@B2.
// shared (ROUTED=false): out[row] = C + b2 (fp32 store)
// routed (ROUTED=true) : ytmp[row] = bf16(C)   (combined later)
template<int K, bool ROUTED>
__global__ __launch_bounds__(256, 2) void k_s2(
    const u16* __restrict__ A, const u16* __restrict__ Bt,
    const float* __restrict__ bias2, float* __restrict__ out,
    u16* __restrict__ ytmp, const int* __restrict__ off_pad)
{
    __shared__ __align__(16) u16 sA[2][128 * 32], sB[2][128 * 32];  // 32 KB
    const int nwg = gridDim.x * gridDim.y;
    const int id  = xcd_swz(blockIdx.y * gridDim.x + blockIdx.x, nwg);
    const int m0 = (id / gridDim.x) * 128;
    const int n0 = (id % gridDim.x) * 128;
    if (ROUTED && m0 >= off_pad[NEXP]) return;
    const u16* bt = Bt;
    if (ROUTED) {
        int e = 0;
        while (off_pad[e + 1] <= m0) e++;
        bt += (size_t)e * DDIM * IDIM;
    }
    const int tid = threadIdx.x;
    const int wid = tid >> 6, lane = tid & 63;
    const int srow = wid * 16 + (lane >> 2);
    const int skk  = (lane & 3) * 8;
    const u16* gA = A  + (size_t)(m0 + srow) * K + skk;
    const u16* gB = bt + (size_t)(n0 + srow) * K + skk;
    const int ldst = wid * 512;
    const int fr = lane & 15;
    const int fk = (lane >> 4) * 8;
    const int wrow = (wid >> 1) * 64, wcol = (wid & 1) * 64;

    f32x4 acc[4][4];
#pragma unroll
    for (int i = 0; i < 4; i++)
#pragma unroll
        for (int j = 0; j < 4; j++) acc[i][j] = {0.f, 0.f, 0.f, 0.f};

#pragma unroll
    for (int p = 0; p < 2; p++) {
        gload_lds16(gA + (size_t)p * 64 * K, &sA[0][ldst + p * 2048]);
        gload_lds16(gB + (size_t)p * 64 * K, &sB[0][ldst + p * 2048]);
    }
    __syncthreads();

    int cur = 0;
    for (int k0 = 0; k0 < K; k0 += 32) {
        if (k0 + 32 < K) {
#pragma unroll
            for (int p = 0; p < 2; p++) {
                gload_lds16(gA + (size_t)p * 64 * K + k0 + 32, &sA[cur ^ 1][ldst + p * 2048]);
                gload_lds16(gB + (size_t)p * 64 * K + k0 + 32, &sB[cur ^ 1][ldst + p * 2048]);
            }
        }
        bf16x8 av[4], bv[4];
#pragma unroll
        for (int i = 0; i < 4; i++) {
            av[i] = *(const bf16x8*)(&sA[cur][(wrow + i * 16 + fr) * 32 + fk]);
            bv[i] = *(const bf16x8*)(&sB[cur][(wcol + i * 16 + fr) * 32 + fk]);
        }
#pragma unroll
        for (int i = 0; i < 4; i++)
#pragma unroll
            for (int j = 0; j < 4; j++)
                acc[i][j] = __builtin_amdgcn_mfma_f32_16x16x32_bf16(av[i], bv[j], acc[i][j], 0, 0, 0);
        __syncthreads();
        cur ^= 1;
    }

    const int rr = (lane >> 4) * 4;
#pragma unroll
    for (int i = 0; i < 4; i++) {
#pragma unroll
        for (int r = 0; r < 4; r++) {
            int row = m0 + wrow + i * 16 + rr + r;
#pragma unroll
            for (int j = 0; j < 4; j++) {
                int col = n0 + wcol + j * 16 + fr;
                float v = acc[i][j][r];
                if (ROUTED) {
                    ytmp[(size_t)row * DDIM + col] = f2bf(v);
                } else {
                    out[(size_t)row * DDIM + col] = v + bias2[col];
                }
            }
        }
    }
}

// out[t] += wts[2t]*ytmp[inv[2t]] + wts[2t+1]*ytmp[inv[2t+1]]
__global__ __launch_bounds__(256) void k_combine(
    const u16* __restrict__ ytmp, const int* __restrict__ inv,
    const float* __restrict__ wts, float* __restrict__ out)
{
    int idx = blockIdx.x * 256 + threadIdx.x;   // one thread per 4 elems
    int t = idx >> 7;
    int c = (idx & 127) * 4;
    int s0 = inv[2 * t], s1 = inv[2 * t + 1];
    float w0 = wts[2 * t], w1 = wts[2 * t + 1];
    ushort4 a = *(const ushort4*)&ytmp[(size_t)s0 * DDIM + c];
    ushort4 b = *(const ushort4*)&ytmp[(size_t)s1 * DDIM + c];
    float4 o = *(float4*)&out[(size_t)t * DDIM + c];
    o.x += w0 * bf2f(a.x) + w1 * bf2f(b.x);
    o.y += w0 * bf2f(a.y) + w1 * bf2f(b.y);
    o.z += w0 * bf2f(a.z) + w1 * bf2f(b.z);
    o.w += w0 * bf2f(a.w) + w1 * bf2f(b.w);
    *(float4*)&out[(size_t)t * DDIM + c] = o;
}

// ---------------- launch ----------------
extern "C" void kernel_launch(void* const* d_in, const int* in_sizes, int n_in,
                              void* d_out, int out_size, void* d_ws, size_t ws_size,
                              hipStream_t stream)
{
    const float* x   = (const float*)d_in[0];
    const float* gw  = (const float*)d_in[1];
    const float* w1  = (const float*)d_in[2];
    const float* w2  = (const float*)d_in[3];
    const float* w3  = (const float*)d_in[4];
    const float* sw1 = (const float*)d_in[5];
    const float* sb1 = (const float*)d_in[6];
    const float* sw2 = (const float*)d_in[7];
    const float* sb2 = (const float*)d_in[8];
    const float* sw3 = (const float*)d_in[9];
    const float* sb3 = (const float*)d_in[10];
    float* out = (float*)d_out;

    char* ws = (char*)d_ws;
    size_t off = 0;
    int*   topi    = (int*)(ws + off);   off += (size_t)2 * T_TOK * 4;
    float* wts     = (float*)(ws + off); off += (size_t)2 * T_TOK * 4;
    int*   perm    = (int*)(ws + off);   off += (size_t)MPAD * 4;
    float* pw      = (float*)(ws + off); off += (size_t)MPAD * 4;
    int*   cursors = (int*)(ws + off);   off += 256;
    int*   off_pad = (int*)(ws + off);   off += 256;
    int*   pcnt    = (int*)(ws + off);   off += (size_t)GBLK * NEXP * 4;
    float* pps     = (float*)(ws + off); off += (size_t)GBLK * NEXP * 4;
    int*   inv     = (int*)(ws + off);   off += (size_t)2 * T_TOK * 4;
    u16*   xb      = (u16*)(ws + off);   off += (size_t)T_TOK * DDIM * 2;
    u16*   xg      = (u16*)(ws + off);   off += (size_t)MPAD * DDIM * 2;
    u16*   w1T     = (u16*)(ws + off);   off += (size_t)NEXP * IDIM * DDIM * 2;
    u16*   w3T     = (u16*)(ws + off);   off += (size_t)NEXP * IDIM * DDIM * 2;
    u16*   w2T     = (u16*)(ws + off);   off += (size_t)NEXP * DDIM * IDIM * 2;
    u16*   sw1T    = (u16*)(ws + off);   off += (size_t)SHDIM * DDIM * 2;
    u16*   sw3T    = (u16*)(ws + off);   off += (size_t)SHDIM * DDIM * 2;
    u16*   sw2T    = (u16*)(ws + off);   off += (size_t)DDIM * SHDIM * 2;
    u16*   hb      = (u16*)(ws + off);   off += (size_t)MPAD * IDIM * 2;
    u16*   ytmp    = xg;   // xg is dead after routed s1's staging reads; reuse (same size)

    // routing
    k_zero<<<1, 64, 0, stream>>>(cursors);
    k_gate<<<GBLK, 256, 0, stream>>>(x, gw, topi, wts, pcnt, pps, xb);
    k_scan<<<1, 64, 0, stream>>>(pcnt, pps, off_pad, out + (size_t)T_TOK * DDIM);
    k_fillperm<<<(MPAD + 255) / 256, 256, 0, stream>>>(perm);
    k_scatter<<<T_TOK / 256, 256, 0, stream>>>(topi, wts, off_pad, cursors, perm, pw, inv);

    // conversions
    k_gather<<<MPAD / 2, 256, 0, stream>>>(xb, perm, xg);
    k_transpose<<<dim3(IDIM / 64, DDIM / 64, NEXP), 256, 0, stream>>>(w1, w1T, DDIM, IDIM);
    k_transpose<<<dim3(IDIM / 64, DDIM / 64, NEXP), 256, 0, stream>>>(w3, w3T, DDIM, IDIM);
    k_transpose<<<dim3(DDIM / 64, IDIM / 64, NEXP), 256, 0, stream>>>(w2, w2T, IDIM, DDIM);
    k_transpose<<<dim3(SHDIM / 64, DDIM / 64, 1), 256, 0, stream>>>(sw1, sw1T, DDIM, SHDIM);
    k_transpose<<<dim3(SHDIM / 64, DDIM / 64, 1), 256, 0, stream>>>(sw3, sw3T, DDIM, SHDIM);
    k_transpose<<<dim3(DDIM / 64, SHDIM / 64, 1), 256, 0, stream>>>(sw2, sw2T, SHDIM, DDIM);

    // shared expert (writes out = z)
    k_s1<DDIM, false, true><<<dim3(SHDIM / 128, T_TOK / 128), 256, 0, stream>>>(
        xb, sw1T, sw3T, sb1, sb3, hb, SHDIM, nullptr);
    k_s2<SHDIM, false><<<dim3(DDIM / 128, T_TOK / 128), 256, 0, stream>>>(
        hb, sw2T, sb2, out, nullptr, nullptr);
    // routed experts -> ytmp, then combine into out
    k_s1<DDIM, true, false><<<dim3(IDIM / 128, MT_R), 256, 0, stream>>>(
        xg, w1T, w3T, nullptr, nullptr, hb, IDIM, off_pad);
    k_s2<IDIM, true><<<dim3(DDIM / 128, MT_R), 256, 0, stream>>>(
        hb, w2T, nullptr, nullptr, ytmp, off_pad);
    k_combine<<<(T_TOK * DDIM / 4) / 256, 256, 0, stream>>>(ytmp, inv, wts, out);
}